// Round 1
// baseline (199.358 us; speedup 1.0000x reference)
//
#include <hip/hip_runtime.h>

#define BB 16
#define NN 1024
#define CC 64
#define TJ 128           // j-tile
#define IR 32            // rows per block
#define AW_STRIDE 132    // 128 + 4 pad (breaks row-broadcast bank aliasing)

typedef __attribute__((address_space(3))) void lds_void_t;
typedef const __attribute__((address_space(1))) void gbl_void_t;

__device__ __forceinline__ void load_lds16(const void* g, void* l) {
    __builtin_amdgcn_global_load_lds((gbl_void_t*)g, (lds_void_t*)l, 16, 0, 0);
}

// ---------------- Kernel 1: xw = x @ W_rel, xr = x @ W_root ----------------
// grid = B*N/16 blocks x 256 threads; each block does 16 rows.
extern "C" __global__ __launch_bounds__(256)
void precompute_xw(const float* __restrict__ x, const float* __restrict__ W_rel,
                   const float* __restrict__ W_root,
                   float* __restrict__ xw, float* __restrict__ xr)
{
    __shared__ float wrel_s[64 * 64];
    __shared__ float wroot_s[64 * 64];
    __shared__ float x_s[16 * 68];       // stride 68: conflict-free row broadcast

    const int t = threadIdx.x;
    // Stage weights: 4096 floats each = 1024 float4 each.
    #pragma unroll
    for (int k = 0; k < 4; ++k) {
        int i4 = t + 256 * k;
        ((float4*)wrel_s)[i4]  = ((const float4*)W_rel)[i4];
        ((float4*)wroot_s)[i4] = ((const float4*)W_root)[i4];
    }
    const int row0 = blockIdx.x * 16;
    {
        int r = t >> 4, c4 = t & 15;
        *(float4*)(x_s + r * 68 + c4 * 4) = ((const float4*)(x + (size_t)(row0 + r) * CC))[c4];
    }
    __syncthreads();

    const int c4 = t & 15;
    const int r  = t >> 4;
    float aw0 = 0.f, aw1 = 0.f, aw2 = 0.f, aw3 = 0.f;
    float ar0 = 0.f, ar1 = 0.f, ar2 = 0.f, ar3 = 0.f;
    const float* xrow = x_s + r * 68;
    #pragma unroll 8
    for (int k = 0; k < 64; ++k) {
        float xv = xrow[k];
        float4 wv = ((const float4*)(wrel_s  + k * 64))[c4];
        float4 rv = ((const float4*)(wroot_s + k * 64))[c4];
        aw0 += xv * wv.x; aw1 += xv * wv.y; aw2 += xv * wv.z; aw3 += xv * wv.w;
        ar0 += xv * rv.x; ar1 += xv * rv.y; ar2 += xv * rv.z; ar3 += xv * rv.w;
    }
    const size_t o4 = (size_t)(row0 + r) * (CC / 4) + c4;
    ((float4*)xw)[o4] = make_float4(aw0, aw1, aw2, aw3);
    ((float4*)xr)[o4] = make_float4(ar0, ar1, ar2, ar3);
}

// ---------------- Kernel 2: out = (adj*e) @ xw + b_rel + xr ----------------
// grid = B * (N/IR) = 512 blocks x 256 threads.
// Thread (c4 = t&15, rr = t>>4) owns rows {2rr, 2rr+1} x channels {4c4..4c4+3}.
extern "C" __global__ __launch_bounds__(256)
void gnn_agg(const float* __restrict__ adj, const int* __restrict__ ea,
             const float* __restrict__ w_edge, const float* __restrict__ b_rel,
             const float* __restrict__ xw, const float* __restrict__ xr,
             float* __restrict__ out)
{
    __shared__ float x_s[TJ * CC];          // 32 KiB xw tile (contiguous for global_load_lds)
    __shared__ float aw_s[IR * AW_STRIDE];  // 16.5 KiB weighted-adj tile

    const int t   = threadIdx.x;
    const int bid = blockIdx.x;
    const int b   = bid >> 5;               // 32 row-blocks per batch
    const int i0  = (bid & 31) * IR;

    const float w0 = w_edge[0], w1 = w_edge[1], w2 = w_edge[2], w3 = w_edge[3];
    const int c4 = t & 15;
    const int rr = t >> 4;

    float4 acc0 = make_float4(0.f, 0.f, 0.f, 0.f);
    float4 acc1 = make_float4(0.f, 0.f, 0.f, 0.f);

    const float* adj_base = adj + ((size_t)b * NN + i0) * NN;
    const int*   ea_base  = ea  + ((size_t)b * NN + i0) * NN;
    const float* xw_base  = xw + (size_t)b * NN * CC;

    for (int j0 = 0; j0 < NN; j0 += TJ) {
        // --- stage xw[j0:j0+TJ, :] -> x_s via async global->LDS (contiguous) ---
        {
            const char* src = (const char*)(xw_base + (size_t)j0 * CC);
            char* dst = (char*)x_s;
            #pragma unroll
            for (int k = 0; k < 8; ++k) {
                int off = (t + 256 * k) * 16;
                load_lds16(src + off, dst + off);
            }
        }
        // --- compute weighted-adj tile into aw_s ---
        #pragma unroll
        for (int k = 0; k < 4; ++k) {
            int i4  = t + 256 * k;      // 0..1023 float4 slots
            int row = i4 >> 5;          // 0..31
            int j4  = i4 & 31;          // float4 col
            const float4 av = *(const float4*)(adj_base + (size_t)row * NN + j0 + j4 * 4);
            const int4   iv = *(const int4*)  (ea_base  + (size_t)row * NN + j0 + j4 * 4);
            float4 ev;
            ev.x = av.x * (iv.x == 0 ? w0 : iv.x == 1 ? w1 : iv.x == 2 ? w2 : w3);
            ev.y = av.y * (iv.y == 0 ? w0 : iv.y == 1 ? w1 : iv.y == 2 ? w2 : w3);
            ev.z = av.z * (iv.z == 0 ? w0 : iv.z == 1 ? w1 : iv.z == 2 ? w2 : w3);
            ev.w = av.w * (iv.w == 0 ? w0 : iv.w == 1 ? w1 : iv.w == 2 ? w2 : w3);
            *(float4*)(aw_s + row * AW_STRIDE + j4 * 4) = ev;
        }
        __syncthreads();   // drains global_load_lds (vmcnt) + ds writes

        // --- MAC: 2 rows x 4 channels per thread over the j-tile ---
        const float* awr0 = aw_s + (2 * rr + 0) * AW_STRIDE;
        const float* awr1 = aw_s + (2 * rr + 1) * AW_STRIDE;
        #pragma unroll 8
        for (int j = 0; j < TJ; j += 4) {
            float4 a0 = *(const float4*)(awr0 + j);
            float4 a1 = *(const float4*)(awr1 + j);
            float4 xv0 = ((const float4*)(x_s + (j + 0) * CC))[c4];
            float4 xv1 = ((const float4*)(x_s + (j + 1) * CC))[c4];
            float4 xv2 = ((const float4*)(x_s + (j + 2) * CC))[c4];
            float4 xv3 = ((const float4*)(x_s + (j + 3) * CC))[c4];
            acc0.x += a0.x * xv0.x; acc0.y += a0.x * xv0.y; acc0.z += a0.x * xv0.z; acc0.w += a0.x * xv0.w;
            acc0.x += a0.y * xv1.x; acc0.y += a0.y * xv1.y; acc0.z += a0.y * xv1.z; acc0.w += a0.y * xv1.w;
            acc0.x += a0.z * xv2.x; acc0.y += a0.z * xv2.y; acc0.z += a0.z * xv2.z; acc0.w += a0.z * xv2.w;
            acc0.x += a0.w * xv3.x; acc0.y += a0.w * xv3.y; acc0.z += a0.w * xv3.z; acc0.w += a0.w * xv3.w;
            acc1.x += a1.x * xv0.x; acc1.y += a1.x * xv0.y; acc1.z += a1.x * xv0.z; acc1.w += a1.x * xv0.w;
            acc1.x += a1.y * xv1.x; acc1.y += a1.y * xv1.y; acc1.z += a1.y * xv1.z; acc1.w += a1.y * xv1.w;
            acc1.x += a1.z * xv2.x; acc1.y += a1.z * xv2.y; acc1.z += a1.z * xv2.z; acc1.w += a1.z * xv2.w;
            acc1.x += a1.w * xv3.x; acc1.y += a1.w * xv3.y; acc1.z += a1.w * xv3.z; acc1.w += a1.w * xv3.w;
        }
        __syncthreads();   // protect LDS tiles before next stage
    }

    // --- epilogue: + b_rel + x@W_root ---
    const float4 bv = ((const float4*)b_rel)[c4];
    const size_t row_g = (size_t)b * NN + i0 + 2 * rr;
    const float4* xr4  = (const float4*)(xr  + row_g * CC) + c4;
    float4*       out4 = (float4*)      (out + row_g * CC) + c4;
    float4 r0 = xr4[0];
    float4 r1 = xr4[CC / 4];
    float4 o0 = make_float4(acc0.x + bv.x + r0.x, acc0.y + bv.y + r0.y,
                            acc0.z + bv.z + r0.z, acc0.w + bv.w + r0.w);
    float4 o1 = make_float4(acc1.x + bv.x + r1.x, acc1.y + bv.y + r1.y,
                            acc1.z + bv.z + r1.z, acc1.w + bv.w + r1.w);
    out4[0]      = o0;
    out4[CC / 4] = o1;
}

extern "C" void kernel_launch(void* const* d_in, const int* in_sizes, int n_in,
                              void* d_out, int out_size, void* d_ws, size_t ws_size,
                              hipStream_t stream) {
    const float* x      = (const float*)d_in[0];
    const float* adj    = (const float*)d_in[1];
    const int*   ea     = (const int*)  d_in[2];
    const float* W_rel  = (const float*)d_in[3];
    const float* b_rel  = (const float*)d_in[4];
    const float* W_root = (const float*)d_in[5];
    const float* w_edge = (const float*)d_in[6];
    float* out = (float*)d_out;

    float* xw = (float*)d_ws;                       // [B*N, C]
    float* xr = xw + (size_t)BB * NN * CC;          // [B*N, C]  (needs 8 MiB total ws)

    precompute_xw<<<BB * NN / 16, 256, 0, stream>>>(x, W_rel, W_root, xw, xr);
    gnn_agg<<<BB * (NN / IR), 256, 0, stream>>>(adj, ea, w_edge, b_rel, xw, xr, out);
}

// Round 2
// 178.237 us; speedup vs baseline: 1.1185x; 1.1185x over previous
//
#include <hip/hip_runtime.h>

#define BB 16
#define NN 1024
#define CC 64

typedef __attribute__((ext_vector_type(8))) short short8;
typedef __attribute__((ext_vector_type(4))) float f32x4;

__device__ __forceinline__ unsigned short bf16_rne(float f) {
    unsigned u = __float_as_uint(f);
    u += 0x7fffu + ((u >> 16) & 1u);
    return (unsigned short)(u >> 16);
}

// ---------------- Kernel 1: xw = x@W_rel -> bf16 swizzled (B-frag order);
//                  out = x@W_root + b_rel (fp32) ----------------
// grid = B*N/16 = 1024 blocks x 256 threads; block does 16 rows.
extern "C" __global__ __launch_bounds__(256)
void precompute(const float* __restrict__ x, const float* __restrict__ W_rel,
                const float* __restrict__ W_root, const float* __restrict__ b_rel,
                unsigned short* __restrict__ xw_sw, float* __restrict__ out)
{
    __shared__ float wrel_s[64 * 64];
    __shared__ float wroot_s[64 * 64];
    __shared__ float x_s[16 * 68];

    const int t = threadIdx.x;
    #pragma unroll
    for (int k = 0; k < 4; ++k) {
        int i4 = t + 256 * k;
        ((float4*)wrel_s)[i4]  = ((const float4*)W_rel)[i4];
        ((float4*)wroot_s)[i4] = ((const float4*)W_root)[i4];
    }
    const int row0 = blockIdx.x * 16;
    {
        int r = t >> 4, c4 = t & 15;
        *(float4*)(x_s + r * 68 + c4 * 4) = ((const float4*)(x + (size_t)(row0 + r) * CC))[c4];
    }
    __syncthreads();

    const int c4 = t & 15;     // channel group: c = 4*c4 .. +3
    const int r  = t >> 4;     // local row
    float aw0 = 0.f, aw1 = 0.f, aw2 = 0.f, aw3 = 0.f;
    float ar0 = 0.f, ar1 = 0.f, ar2 = 0.f, ar3 = 0.f;
    const float* xrow = x_s + r * 68;
    #pragma unroll 8
    for (int k = 0; k < 64; ++k) {
        float xv = xrow[k];
        float4 wv = ((const float4*)(wrel_s  + k * 64))[c4];
        float4 rv = ((const float4*)(wroot_s + k * 64))[c4];
        aw0 += xv * wv.x; aw1 += xv * wv.y; aw2 += xv * wv.z; aw3 += xv * wv.w;
        ar0 += xv * rv.x; ar1 += xv * rv.y; ar2 += xv * rv.z; ar3 += xv * rv.w;
    }

    const int row_g = row0 + r;              // global row over B*N
    // out = x@W_root + b_rel
    {
        const float4 bv = ((const float4*)b_rel)[c4];
        ((float4*)out)[(size_t)row_g * 16 + c4] =
            make_float4(ar0 + bv.x, ar1 + bv.y, ar2 + bv.z, ar3 + bv.w);
    }
    // xw -> bf16, swizzled B-frag layout:
    // per batch: tile (kb, n0) of [32k x 16n] = 512 bf16; slot = lane*8 + j,
    // lane = n + 16*((k>>3)&3), j = k&7, kb = k>>5, n = c&15, n0 = c>>4.
    {
        const int b = row_g >> 10;
        const int k = row_g & 1023;
        const int kb = k >> 5;
        const int qk = (k >> 3) & 3;
        const int j  = k & 7;
        const int c  = 4 * c4;
        const int n0 = c >> 4;
        const int n  = c & 15;
        size_t off = ((size_t)b << 16) + (size_t)((kb * 4 + n0) << 9)
                   + (size_t)((n + (qk << 4)) << 3) + j;
        xw_sw[off]      = bf16_rne(aw0);
        xw_sw[off + 8]  = bf16_rne(aw1);
        xw_sw[off + 16] = bf16_rne(aw2);
        xw_sw[off + 24] = bf16_rne(aw3);
    }
}

// ---------------- Kernel 2: out += (adj .* w_edge[ea]) @ xw  (bf16 MFMA) ----
// grid = B * (N/16) = 1024 blocks x 256 threads.
// Block = one 16-row m-tile of one batch; wave w handles k in [w*256, w*256+256).
// A-frags built in registers from global adj/ea; B-frags from swizzled global xw.
extern "C" __global__ __launch_bounds__(256, 4)
void gnn_mfma(const float* __restrict__ adj, const int* __restrict__ ea,
              const float* __restrict__ w_edge,
              const unsigned short* __restrict__ xw_sw,
              float* __restrict__ out)
{
    __shared__ float red_s[3 * 16 * 64];   // partials from waves 1..3

    const int t    = threadIdx.x;
    const int w    = t >> 6;               // k-quarter 0..3
    const int lane = t & 63;
    const int m    = lane & 15;
    const int q    = lane >> 4;
    const int b     = blockIdx.x >> 6;
    const int mtile = blockIdx.x & 63;

    // cubic through (e, w_edge[e]) for e=0..3 — exact gather without branches
    const float w0 = w_edge[0], w1 = w_edge[1], w2 = w_edge[2], w3 = w_edge[3];
    const float d1 = w1 - w0;
    const float d2 = w2 - 2.f * w1 + w0;
    const float d3 = w3 - 3.f * w2 + 3.f * w1 - w0;
    const float c3 = d3 * (1.f / 6.f);
    const float c2 = 0.5f * d2 - 0.5f * d3;
    const float c1 = d1 - 0.5f * d2 + (1.f / 3.f) * d3;
    const float c0 = w0;

    const int row = (mtile << 4) + m;
    const float* arow = adj + (((size_t)b << 10) + row) * NN + (w << 8) + (q << 3);
    const int*   erow = ea  + (((size_t)b << 10) + row) * NN + (w << 8) + (q << 3);
    const short8* xf  = (const short8*)(xw_sw + ((size_t)b << 16) + (w << 14)) + lane;
    // B-frag (kk, n0) at xf[(kk*4 + n0)*64]

    f32x4 acc0 = {0.f, 0.f, 0.f, 0.f};
    f32x4 acc1 = acc0, acc2 = acc0, acc3 = acc0;

    #pragma unroll 2
    for (int kk = 0; kk < 8; ++kk) {
        const float* ap = arow + (kk << 5);
        const int*   ep = erow + (kk << 5);
        float4 a0 = *(const float4*)ap;
        float4 a1 = *(const float4*)(ap + 4);
        int4   e0 = *(const int4*)ep;
        int4   e1 = *(const int4*)(ep + 4);

        #define WSEL(e) __builtin_fmaf(__builtin_fmaf(__builtin_fmaf(c3, (float)(e), c2), (float)(e), c1), (float)(e), c0)
        float p0 = a0.x * WSEL(e0.x);
        float p1 = a0.y * WSEL(e0.y);
        float p2 = a0.z * WSEL(e0.z);
        float p3 = a0.w * WSEL(e0.w);
        float p4 = a1.x * WSEL(e1.x);
        float p5 = a1.y * WSEL(e1.y);
        float p6 = a1.z * WSEL(e1.z);
        float p7 = a1.w * WSEL(e1.w);
        #undef WSEL

        // pack hi16 of float pairs -> bf16x2 (truncation; 1 v_perm per pair)
        union { int i[4]; short8 s; } af;
        af.i[0] = __builtin_amdgcn_perm(__float_as_uint(p1), __float_as_uint(p0), 0x07060302u);
        af.i[1] = __builtin_amdgcn_perm(__float_as_uint(p3), __float_as_uint(p2), 0x07060302u);
        af.i[2] = __builtin_amdgcn_perm(__float_as_uint(p5), __float_as_uint(p4), 0x07060302u);
        af.i[3] = __builtin_amdgcn_perm(__float_as_uint(p7), __float_as_uint(p6), 0x07060302u);

        short8 bf0 = xf[(kk * 4 + 0) * 64];
        short8 bf1 = xf[(kk * 4 + 1) * 64];
        short8 bf2 = xf[(kk * 4 + 2) * 64];
        short8 bf3 = xf[(kk * 4 + 3) * 64];

        acc0 = __builtin_amdgcn_mfma_f32_16x16x32_bf16(af.s, bf0, acc0, 0, 0, 0);
        acc1 = __builtin_amdgcn_mfma_f32_16x16x32_bf16(af.s, bf1, acc1, 0, 0, 0);
        acc2 = __builtin_amdgcn_mfma_f32_16x16x32_bf16(af.s, bf2, acc2, 0, 0, 0);
        acc3 = __builtin_amdgcn_mfma_f32_16x16x32_bf16(af.s, bf3, acc3, 0, 0, 0);
    }

    // reduce 4 k-quarter partials within the block; wave 0 owns the RMW to out.
    // C/D layout: col = n0*16 + (lane&15), row = (lane>>4)*4 + reg.
    if (w != 0) {
        float* buf = red_s + (w - 1) * 1024;
        #pragma unroll
        for (int rg = 0; rg < 4; ++rg) {
            int rbase = (q * 4 + rg) * 64 + m;
            buf[rbase]      = acc0[rg];
            buf[rbase + 16] = acc1[rg];
            buf[rbase + 32] = acc2[rg];
            buf[rbase + 48] = acc3[rg];
        }
    }
    __syncthreads();
    if (w == 0) {
        float* obase = out + (((size_t)b << 10) + (mtile << 4)) * 64;
        #pragma unroll
        for (int rg = 0; rg < 4; ++rg) {
            int rbase = (q * 4 + rg) * 64 + m;
            #pragma unroll
            for (int n0 = 0; n0 < 4; ++n0) {
                int idx = rbase + n0 * 16;
                float v = (n0 == 0 ? acc0[rg] : n0 == 1 ? acc1[rg] : n0 == 2 ? acc2[rg] : acc3[rg]);
                v += red_s[idx] + red_s[1024 + idx] + red_s[2048 + idx];
                obase[idx] += v;
            }
        }
    }
}

extern "C" void kernel_launch(void* const* d_in, const int* in_sizes, int n_in,
                              void* d_out, int out_size, void* d_ws, size_t ws_size,
                              hipStream_t stream) {
    const float* x      = (const float*)d_in[0];
    const float* adj    = (const float*)d_in[1];
    const int*   ea     = (const int*)  d_in[2];
    const float* W_rel  = (const float*)d_in[3];
    const float* b_rel  = (const float*)d_in[4];
    const float* W_root = (const float*)d_in[5];
    const float* w_edge = (const float*)d_in[6];
    float* out = (float*)d_out;

    unsigned short* xw_sw = (unsigned short*)d_ws;   // B*N*C bf16 = 2 MiB

    precompute<<<BB * NN / 16, 256, 0, stream>>>(x, W_rel, W_root, b_rel, xw_sw, out);
    gnn_mfma<<<BB * (NN / 16), 256, 0, stream>>>(adj, ea, w_edge, xw_sw, out);
}

// Round 3
// 175.998 us; speedup vs baseline: 1.1327x; 1.0127x over previous
//
#include <hip/hip_runtime.h>

#define BB 16
#define NN 1024
#define CC 64

typedef __attribute__((ext_vector_type(8))) short short8;
typedef __attribute__((ext_vector_type(4))) float f32x4;

__device__ __forceinline__ unsigned short bf16_rne(float f) {
    unsigned u = __float_as_uint(f);
    u += 0x7fffu + ((u >> 16) & 1u);
    return (unsigned short)(u >> 16);
}

// ---------------- Kernel 1: xw = x@W_rel -> bf16 swizzled (B-frag order);
//                  out = x@W_root + b_rel (fp32) ----------------
extern "C" __global__ __launch_bounds__(256)
void precompute(const float* __restrict__ x, const float* __restrict__ W_rel,
                const float* __restrict__ W_root, const float* __restrict__ b_rel,
                unsigned short* __restrict__ xw_sw, float* __restrict__ out)
{
    __shared__ float wrel_s[64 * 64];
    __shared__ float wroot_s[64 * 64];
    __shared__ float x_s[16 * 68];

    const int t = threadIdx.x;
    #pragma unroll
    for (int k = 0; k < 4; ++k) {
        int i4 = t + 256 * k;
        ((float4*)wrel_s)[i4]  = ((const float4*)W_rel)[i4];
        ((float4*)wroot_s)[i4] = ((const float4*)W_root)[i4];
    }
    const int row0 = blockIdx.x * 16;
    {
        int r = t >> 4, c4 = t & 15;
        *(float4*)(x_s + r * 68 + c4 * 4) = ((const float4*)(x + (size_t)(row0 + r) * CC))[c4];
    }
    __syncthreads();

    const int c4 = t & 15;
    const int r  = t >> 4;
    float aw0 = 0.f, aw1 = 0.f, aw2 = 0.f, aw3 = 0.f;
    float ar0 = 0.f, ar1 = 0.f, ar2 = 0.f, ar3 = 0.f;
    const float* xrow = x_s + r * 68;
    #pragma unroll 8
    for (int k = 0; k < 64; ++k) {
        float xv = xrow[k];
        float4 wv = ((const float4*)(wrel_s  + k * 64))[c4];
        float4 rv = ((const float4*)(wroot_s + k * 64))[c4];
        aw0 += xv * wv.x; aw1 += xv * wv.y; aw2 += xv * wv.z; aw3 += xv * wv.w;
        ar0 += xv * rv.x; ar1 += xv * rv.y; ar2 += xv * rv.z; ar3 += xv * rv.w;
    }

    const int row_g = row0 + r;
    {
        const float4 bv = ((const float4*)b_rel)[c4];
        ((float4*)out)[(size_t)row_g * 16 + c4] =
            make_float4(ar0 + bv.x, ar1 + bv.y, ar2 + bv.z, ar3 + bv.w);
    }
    {
        const int b = row_g >> 10;
        const int k = row_g & 1023;
        const int kb = k >> 5;
        const int qk = (k >> 3) & 3;
        const int j  = k & 7;
        const int c  = 4 * c4;
        const int n0 = c >> 4;
        const int n  = c & 15;
        size_t off = ((size_t)b << 16) + (size_t)((kb * 4 + n0) << 9)
                   + (size_t)((n + (qk << 4)) << 3) + j;
        xw_sw[off]      = bf16_rne(aw0);
        xw_sw[off + 8]  = bf16_rne(aw1);
        xw_sw[off + 16] = bf16_rne(aw2);
        xw_sw[off + 24] = bf16_rne(aw3);
    }
}

// ---------------- Kernel 2: out += (adj .* w_edge[ea]) @ xw  (bf16 MFMA) ----
// grid = B * (N/16) = 1024 blocks x 256 threads.
// Wave w handles K-slice [w*256, (w+1)*256). ALL adj/ea for the slice loaded
// up front into registers (32 x 16B = 128 lines in flight per wave) so the
// kernel runs at memory-BW, not serialized-latency, speed.
extern "C" __global__ __launch_bounds__(256, 2)
void gnn_mfma(const float* __restrict__ adj, const int* __restrict__ ea,
              const float* __restrict__ w_edge,
              const unsigned short* __restrict__ xw_sw,
              float* __restrict__ out)
{
    __shared__ float red_s[3 * 1088];      // 3 waves x 16 rows x stride 68

    const int t    = threadIdx.x;
    const int w    = t >> 6;
    const int lane = t & 63;
    const int m    = lane & 15;
    const int q    = lane >> 4;
    const int b     = blockIdx.x >> 6;
    const int mtile = blockIdx.x & 63;

    // cubic through (e, w_edge[e]) for e=0..3 — exact branchless gather
    const float w0 = w_edge[0], w1 = w_edge[1], w2 = w_edge[2], w3 = w_edge[3];
    const float d1 = w1 - w0;
    const float d2 = w2 - 2.f * w1 + w0;
    const float d3 = w3 - 3.f * w2 + 3.f * w1 - w0;
    const float c3 = d3 * (1.f / 6.f);
    const float c2 = 0.5f * d2 - 0.5f * d3;
    const float c1 = d1 - 0.5f * d2 + (1.f / 3.f) * d3;
    const float c0 = w0;

    const int row = (mtile << 4) + m;
    const size_t rowoff = (((size_t)b << 10) + row) * NN + (w << 8) + (q << 3);
    const float* arow = adj + rowoff;
    const int*   erow = ea  + rowoff;
    const short8* xf  = (const short8*)(xw_sw + ((size_t)b << 16)) + lane;

    // ---- issue ALL slice loads up front (deep MLP), then fence scheduling ----
    float4 a[8][2];
    int4   e[8][2];
    #pragma unroll
    for (int kk = 0; kk < 8; ++kk) {
        a[kk][0] = *(const float4*)(arow + (kk << 5));
        a[kk][1] = *(const float4*)(arow + (kk << 5) + 4);
        e[kk][0] = *(const int4*)  (erow + (kk << 5));
        e[kk][1] = *(const int4*)  (erow + (kk << 5) + 4);
    }
    short8 bf0 = xf[((w * 8 + 0) * 4 + 0) * 64];
    short8 bf1 = xf[((w * 8 + 0) * 4 + 1) * 64];
    short8 bf2 = xf[((w * 8 + 0) * 4 + 2) * 64];
    short8 bf3 = xf[((w * 8 + 0) * 4 + 3) * 64];
    __builtin_amdgcn_sched_barrier(0);     // keep loads above all compute

    f32x4 acc0 = {0.f, 0.f, 0.f, 0.f};
    f32x4 acc1 = acc0, acc2 = acc0, acc3 = acc0;

    #pragma unroll
    for (int kk = 0; kk < 8; ++kk) {
        // prefetch next kk's B-frags (L2-hot) before using this kk's
        short8 nb0, nb1, nb2, nb3;
        if (kk < 7) {
            nb0 = xf[((w * 8 + kk + 1) * 4 + 0) * 64];
            nb1 = xf[((w * 8 + kk + 1) * 4 + 1) * 64];
            nb2 = xf[((w * 8 + kk + 1) * 4 + 2) * 64];
            nb3 = xf[((w * 8 + kk + 1) * 4 + 3) * 64];
        }
        float4 a0 = a[kk][0], a1 = a[kk][1];
        int4   e0 = e[kk][0], e1 = e[kk][1];

        #define WSEL(ev) __builtin_fmaf(__builtin_fmaf(__builtin_fmaf(c3, (float)(ev), c2), (float)(ev), c1), (float)(ev), c0)
        float p0 = a0.x * WSEL(e0.x);
        float p1 = a0.y * WSEL(e0.y);
        float p2 = a0.z * WSEL(e0.z);
        float p3 = a0.w * WSEL(e0.w);
        float p4 = a1.x * WSEL(e1.x);
        float p5 = a1.y * WSEL(e1.y);
        float p6 = a1.z * WSEL(e1.z);
        float p7 = a1.w * WSEL(e1.w);
        #undef WSEL

        union { int i[4]; short8 s; } af;
        af.i[0] = __builtin_amdgcn_perm(__float_as_uint(p1), __float_as_uint(p0), 0x07060302u);
        af.i[1] = __builtin_amdgcn_perm(__float_as_uint(p3), __float_as_uint(p2), 0x07060302u);
        af.i[2] = __builtin_amdgcn_perm(__float_as_uint(p5), __float_as_uint(p4), 0x07060302u);
        af.i[3] = __builtin_amdgcn_perm(__float_as_uint(p7), __float_as_uint(p6), 0x07060302u);

        acc0 = __builtin_amdgcn_mfma_f32_16x16x32_bf16(af.s, bf0, acc0, 0, 0, 0);
        acc1 = __builtin_amdgcn_mfma_f32_16x16x32_bf16(af.s, bf1, acc1, 0, 0, 0);
        acc2 = __builtin_amdgcn_mfma_f32_16x16x32_bf16(af.s, bf2, acc2, 0, 0, 0);
        acc3 = __builtin_amdgcn_mfma_f32_16x16x32_bf16(af.s, bf3, acc3, 0, 0, 0);

        if (kk < 7) { bf0 = nb0; bf1 = nb1; bf2 = nb2; bf3 = nb3; }
    }

    // ---- cross-wave reduction (stride 68 kills bank conflicts) ----
    if (w != 0) {
        float* buf = red_s + (w - 1) * 1088;
        #pragma unroll
        for (int rg = 0; rg < 4; ++rg) {
            int rbase = (q * 4 + rg) * 68 + m;
            buf[rbase]      = acc0[rg];
            buf[rbase + 16] = acc1[rg];
            buf[rbase + 32] = acc2[rg];
            buf[rbase + 48] = acc3[rg];
        }
    }
    __syncthreads();
    if (w == 0) {
        float* obase = out + (((size_t)b << 10) + (mtile << 4)) * 64;
        #pragma unroll
        for (int rg = 0; rg < 4; ++rg) {
            int rpad = (q * 4 + rg) * 68 + m;
            int rout = (q * 4 + rg) * 64 + m;
            #pragma unroll
            for (int n0 = 0; n0 < 4; ++n0) {
                int idx  = rpad + n0 * 16;
                float v = (n0 == 0 ? acc0[rg] : n0 == 1 ? acc1[rg] : n0 == 2 ? acc2[rg] : acc3[rg]);
                v += red_s[idx] + red_s[1088 + idx] + red_s[2176 + idx];
                obase[rout + n0 * 16] += v;
            }
        }
    }
}

extern "C" void kernel_launch(void* const* d_in, const int* in_sizes, int n_in,
                              void* d_out, int out_size, void* d_ws, size_t ws_size,
                              hipStream_t stream) {
    const float* x      = (const float*)d_in[0];
    const float* adj    = (const float*)d_in[1];
    const int*   ea     = (const int*)  d_in[2];
    const float* W_rel  = (const float*)d_in[3];
    const float* b_rel  = (const float*)d_in[4];
    const float* W_root = (const float*)d_in[5];
    const float* w_edge = (const float*)d_in[6];
    float* out = (float*)d_out;

    unsigned short* xw_sw = (unsigned short*)d_ws;   // B*N*C bf16 = 2 MiB

    precompute<<<BB * NN / 16, 256, 0, stream>>>(x, W_rel, W_root, b_rel, xw_sw, out);
    gnn_mfma<<<BB * (NN / 16), 256, 0, stream>>>(adj, ea, w_edge, xw_sw, out);
}

// Round 4
// 175.631 us; speedup vs baseline: 1.1351x; 1.0021x over previous
//
#include <hip/hip_runtime.h>

#define BB 16
#define NN 1024
#define CC 64

typedef __attribute__((ext_vector_type(8))) short short8;
typedef __attribute__((ext_vector_type(4))) float f32x4;

__device__ __forceinline__ unsigned short bf16_rne(float f) {
    unsigned u = __float_as_uint(f);
    u += 0x7fffu + ((u >> 16) & 1u);
    return (unsigned short)(u >> 16);
}

// ---------------- Kernel 1: xw = x@W_rel -> bf16 swizzled (B-frag order);
//                  out = x@W_root + b_rel (fp32) ----------------
extern "C" __global__ __launch_bounds__(256)
void precompute(const float* __restrict__ x, const float* __restrict__ W_rel,
                const float* __restrict__ W_root, const float* __restrict__ b_rel,
                unsigned short* __restrict__ xw_sw, float* __restrict__ out)
{
    __shared__ float wrel_s[64 * 64];
    __shared__ float wroot_s[64 * 64];
    __shared__ float x_s[16 * 68];

    const int t = threadIdx.x;
    #pragma unroll
    for (int k = 0; k < 4; ++k) {
        int i4 = t + 256 * k;
        ((float4*)wrel_s)[i4]  = ((const float4*)W_rel)[i4];
        ((float4*)wroot_s)[i4] = ((const float4*)W_root)[i4];
    }
    const int row0 = blockIdx.x * 16;
    {
        int r = t >> 4, c4 = t & 15;
        *(float4*)(x_s + r * 68 + c4 * 4) = ((const float4*)(x + (size_t)(row0 + r) * CC))[c4];
    }
    __syncthreads();

    const int c4 = t & 15;
    const int r  = t >> 4;
    float aw0 = 0.f, aw1 = 0.f, aw2 = 0.f, aw3 = 0.f;
    float ar0 = 0.f, ar1 = 0.f, ar2 = 0.f, ar3 = 0.f;
    const float* xrow = x_s + r * 68;
    #pragma unroll 8
    for (int k = 0; k < 64; ++k) {
        float xv = xrow[k];
        float4 wv = ((const float4*)(wrel_s  + k * 64))[c4];
        float4 rv = ((const float4*)(wroot_s + k * 64))[c4];
        aw0 += xv * wv.x; aw1 += xv * wv.y; aw2 += xv * wv.z; aw3 += xv * wv.w;
        ar0 += xv * rv.x; ar1 += xv * rv.y; ar2 += xv * rv.z; ar3 += xv * rv.w;
    }

    const int row_g = row0 + r;
    {
        const float4 bv = ((const float4*)b_rel)[c4];
        ((float4*)out)[(size_t)row_g * 16 + c4] =
            make_float4(ar0 + bv.x, ar1 + bv.y, ar2 + bv.z, ar3 + bv.w);
    }
    {
        const int b = row_g >> 10;
        const int k = row_g & 1023;
        const int kb = k >> 5;
        const int qk = (k >> 3) & 3;
        const int j  = k & 7;
        const int c  = 4 * c4;
        const int n0 = c >> 4;
        const int n  = c & 15;
        size_t off = ((size_t)b << 16) + (size_t)((kb * 4 + n0) << 9)
                   + (size_t)((n + (qk << 4)) << 3) + j;
        xw_sw[off]      = bf16_rne(aw0);
        xw_sw[off + 8]  = bf16_rne(aw1);
        xw_sw[off + 16] = bf16_rne(aw2);
        xw_sw[off + 24] = bf16_rne(aw3);
    }
}

// ---------------- Kernel 2: out += (adj .* w_edge[ea]) @ xw  (bf16 MFMA) ----
// grid = B * (N/16) * 2 = 2048 blocks x 256 threads.
// Block = (batch, m-tile, K-half). Wave w covers K in [khalf*512 + w*128, +128).
// Latency hiding comes from wave count: launch_bounds(256,6) caps VGPR at ~85
// so ~6 blocks (24 waves) fit per CU. Cross-block combine = fp32 atomicAdd.
extern "C" __global__ __launch_bounds__(256, 6)
void gnn_mfma(const float* __restrict__ adj, const int* __restrict__ ea,
              const float* __restrict__ w_edge,
              const unsigned short* __restrict__ xw_sw,
              float* __restrict__ out)
{
    __shared__ float red_s[3 * 1088];      // 3 waves x 16 rows x stride 68

    const int t    = threadIdx.x;
    const int w    = t >> 6;
    const int lane = t & 63;
    const int m    = lane & 15;
    const int q    = lane >> 4;

    const int mtile = blockIdx.x & 63;
    const int khalf = (blockIdx.x >> 6) & 1;
    const int b     = blockIdx.x >> 7;

    // cubic through (e, w_edge[e]) for e=0..3 — exact branchless gather
    const float w0 = w_edge[0], w1 = w_edge[1], w2 = w_edge[2], w3 = w_edge[3];
    const float d1 = w1 - w0;
    const float d2 = w2 - 2.f * w1 + w0;
    const float d3 = w3 - 3.f * w2 + 3.f * w1 - w0;
    const float c3 = d3 * (1.f / 6.f);
    const float c2 = 0.5f * d2 - 0.5f * d3;
    const float c1 = d1 - 0.5f * d2 + (1.f / 3.f) * d3;
    const float c0 = w0;

    const int row = (mtile << 4) + m;
    const size_t rowoff = (((size_t)b << 10) + row) * NN + (khalf << 9) + (w << 7) + (q << 3);
    const float* arow = adj + rowoff;
    const int*   erow = ea  + rowoff;
    const int kb0 = (khalf << 4) + (w << 2);             // first K-block (of 32) for this wave
    const short8* xf = (const short8*)(xw_sw + ((size_t)b << 16)) + lane;

    f32x4 acc0 = {0.f, 0.f, 0.f, 0.f};
    f32x4 acc1 = acc0, acc2 = acc0, acc3 = acc0;

    #pragma unroll
    for (int kk = 0; kk < 4; ++kk) {
        const float* ap = arow + (kk << 5);
        const int*   ep = erow + (kk << 5);
        float4 a0 = *(const float4*)ap;
        float4 a1 = *(const float4*)(ap + 4);
        int4   e0 = *(const int4*)ep;
        int4   e1 = *(const int4*)(ep + 4);
        short8 bf0 = xf[((kb0 + kk) * 4 + 0) * 64];
        short8 bf1 = xf[((kb0 + kk) * 4 + 1) * 64];
        short8 bf2 = xf[((kb0 + kk) * 4 + 2) * 64];
        short8 bf3 = xf[((kb0 + kk) * 4 + 3) * 64];

        #define WSEL(ev) __builtin_fmaf(__builtin_fmaf(__builtin_fmaf(c3, (float)(ev), c2), (float)(ev), c1), (float)(ev), c0)
        float p0 = a0.x * WSEL(e0.x);
        float p1 = a0.y * WSEL(e0.y);
        float p2 = a0.z * WSEL(e0.z);
        float p3 = a0.w * WSEL(e0.w);
        float p4 = a1.x * WSEL(e1.x);
        float p5 = a1.y * WSEL(e1.y);
        float p6 = a1.z * WSEL(e1.z);
        float p7 = a1.w * WSEL(e1.w);
        #undef WSEL

        union { int i[4]; short8 s; } af;
        af.i[0] = __builtin_amdgcn_perm(__float_as_uint(p1), __float_as_uint(p0), 0x07060302u);
        af.i[1] = __builtin_amdgcn_perm(__float_as_uint(p3), __float_as_uint(p2), 0x07060302u);
        af.i[2] = __builtin_amdgcn_perm(__float_as_uint(p5), __float_as_uint(p4), 0x07060302u);
        af.i[3] = __builtin_amdgcn_perm(__float_as_uint(p7), __float_as_uint(p6), 0x07060302u);

        acc0 = __builtin_amdgcn_mfma_f32_16x16x32_bf16(af.s, bf0, acc0, 0, 0, 0);
        acc1 = __builtin_amdgcn_mfma_f32_16x16x32_bf16(af.s, bf1, acc1, 0, 0, 0);
        acc2 = __builtin_amdgcn_mfma_f32_16x16x32_bf16(af.s, bf2, acc2, 0, 0, 0);
        acc3 = __builtin_amdgcn_mfma_f32_16x16x32_bf16(af.s, bf3, acc3, 0, 0, 0);
    }

    // ---- intra-block reduction (stride 68: conflict-free), then atomics ----
    if (w != 0) {
        float* buf = red_s + (w - 1) * 1088;
        #pragma unroll
        for (int rg = 0; rg < 4; ++rg) {
            int rbase = (q * 4 + rg) * 68 + m;
            buf[rbase]      = acc0[rg];
            buf[rbase + 16] = acc1[rg];
            buf[rbase + 32] = acc2[rg];
            buf[rbase + 48] = acc3[rg];
        }
    }
    __syncthreads();
    if (w == 0) {
        float* obase = out + (((size_t)b << 10) + (mtile << 4)) * 64;
        #pragma unroll
        for (int rg = 0; rg < 4; ++rg) {
            int rpad = (q * 4 + rg) * 68 + m;
            int rout = (q * 4 + rg) * 64 + m;
            #pragma unroll
            for (int n0 = 0; n0 < 4; ++n0) {
                int idx = rpad + n0 * 16;
                float v = (n0 == 0 ? acc0[rg] : n0 == 1 ? acc1[rg] : n0 == 2 ? acc2[rg] : acc3[rg]);
                v += red_s[idx] + red_s[1088 + idx] + red_s[2176 + idx];
                atomicAdd(obase + rout + n0 * 16, v);
            }
        }
    }
}

extern "C" void kernel_launch(void* const* d_in, const int* in_sizes, int n_in,
                              void* d_out, int out_size, void* d_ws, size_t ws_size,
                              hipStream_t stream) {
    const float* x      = (const float*)d_in[0];
    const float* adj    = (const float*)d_in[1];
    const int*   ea     = (const int*)  d_in[2];
    const float* W_rel  = (const float*)d_in[3];
    const float* b_rel  = (const float*)d_in[4];
    const float* W_root = (const float*)d_in[5];
    const float* w_edge = (const float*)d_in[6];
    float* out = (float*)d_out;

    unsigned short* xw_sw = (unsigned short*)d_ws;   // B*N*C bf16 = 2 MiB

    precompute<<<BB * NN / 16, 256, 0, stream>>>(x, W_rel, W_root, b_rel, xw_sw, out);
    gnn_mfma<<<BB * (NN / 16) * 2, 256, 0, stream>>>(adj, ea, w_edge, xw_sw, out);
}

// Round 5
// 170.926 us; speedup vs baseline: 1.1663x; 1.0275x over previous
//
#include <hip/hip_runtime.h>

#define BB 16
#define NN 1024
#define CC 64

typedef __attribute__((ext_vector_type(8))) short short8;
typedef __attribute__((ext_vector_type(4))) float f32x4;
typedef __attribute__((ext_vector_type(4))) int   i32x4;

typedef __attribute__((address_space(3))) void lds_void_t;
typedef const __attribute__((address_space(1))) void gbl_void_t;

__device__ __forceinline__ void load_lds16(const void* g, void* l) {
    __builtin_amdgcn_global_load_lds((gbl_void_t*)g, (lds_void_t*)l, 16, 0, 0);
}

__device__ __forceinline__ unsigned short bf16_rne(float f) {
    unsigned u = __float_as_uint(f);
    u += 0x7fffu + ((u >> 16) & 1u);
    return (unsigned short)(u >> 16);
}

// ---------------- Kernel 1: xw = x@W_rel -> bf16 swizzled (B-frag order);
//                  out = x@W_root + b_rel (fp32) ----------------
extern "C" __global__ __launch_bounds__(256)
void precompute(const float* __restrict__ x, const float* __restrict__ W_rel,
                const float* __restrict__ W_root, const float* __restrict__ b_rel,
                unsigned short* __restrict__ xw_sw, float* __restrict__ out)
{
    __shared__ float wrel_s[64 * 64];
    __shared__ float wroot_s[64 * 64];
    __shared__ float x_s[16 * 68];

    const int t = threadIdx.x;
    #pragma unroll
    for (int k = 0; k < 4; ++k) {
        int i4 = t + 256 * k;
        ((float4*)wrel_s)[i4]  = ((const float4*)W_rel)[i4];
        ((float4*)wroot_s)[i4] = ((const float4*)W_root)[i4];
    }
    const int row0 = blockIdx.x * 16;
    {
        int r = t >> 4, c4 = t & 15;
        *(float4*)(x_s + r * 68 + c4 * 4) = ((const float4*)(x + (size_t)(row0 + r) * CC))[c4];
    }
    __syncthreads();

    const int c4 = t & 15;
    const int r  = t >> 4;
    float aw0 = 0.f, aw1 = 0.f, aw2 = 0.f, aw3 = 0.f;
    float ar0 = 0.f, ar1 = 0.f, ar2 = 0.f, ar3 = 0.f;
    const float* xrow = x_s + r * 68;
    #pragma unroll 8
    for (int k = 0; k < 64; ++k) {
        float xv = xrow[k];
        float4 wv = ((const float4*)(wrel_s  + k * 64))[c4];
        float4 rv = ((const float4*)(wroot_s + k * 64))[c4];
        aw0 += xv * wv.x; aw1 += xv * wv.y; aw2 += xv * wv.z; aw3 += xv * wv.w;
        ar0 += xv * rv.x; ar1 += xv * rv.y; ar2 += xv * rv.z; ar3 += xv * rv.w;
    }

    const int row_g = row0 + r;
    {
        const float4 bv = ((const float4*)b_rel)[c4];
        ((float4*)out)[(size_t)row_g * 16 + c4] =
            make_float4(ar0 + bv.x, ar1 + bv.y, ar2 + bv.z, ar3 + bv.w);
    }
    {
        const int b = row_g >> 10;
        const int k = row_g & 1023;
        const int kb = k >> 5;
        const int qk = (k >> 3) & 3;
        const int j  = k & 7;
        const int c  = 4 * c4;
        const int n0 = c >> 4;
        const int n  = c & 15;
        size_t off = ((size_t)b << 16) + (size_t)((kb * 4 + n0) << 9)
                   + (size_t)((n + (qk << 4)) << 3) + j;
        xw_sw[off]      = bf16_rne(aw0);
        xw_sw[off + 8]  = bf16_rne(aw1);
        xw_sw[off + 16] = bf16_rne(aw2);
        xw_sw[off + 24] = bf16_rne(aw3);
    }
}

// ---------------- Kernel 2: out += (adj .* w_edge[ea]) @ xw  (bf16 MFMA) ----
// grid = B * (N/32) * 2 = 1024 blocks x 256 threads.
// Block = (batch b, 32-row m-tile, K-half of 512). K staged in 4 chunks of 128
// via global_load_lds (deep async queue -> no VGPR-serialization ceiling):
//   adj/ea staged directly in MFMA A-fragment lane order,
//   xw staged from its B-frag-order global layout.
// Waves: (wm = rows 16-half, wk = k 64-half of each chunk). LDS 48 KB -> 3 blk/CU.
#define ADJ_OFF 0
#define EA_OFF  16384
#define XW_OFF  32768

extern "C" __global__ __launch_bounds__(256, 3)
void gnn_mfma(const float* __restrict__ adj, const int* __restrict__ ea,
              const float* __restrict__ w_edge,
              const unsigned short* __restrict__ xw_sw,
              float* __restrict__ out)
{
    __shared__ __align__(16) char lds[49152];

    const int t    = threadIdx.x;
    const int w    = t >> 6;
    const int lane = t & 63;
    const int m    = lane & 15;
    const int q    = lane >> 4;
    const int wm   = w >> 1;
    const int wk   = w & 1;

    const int mtile = blockIdx.x & 31;
    const int kh    = (blockIdx.x >> 5) & 1;
    const int b     = blockIdx.x >> 6;
    const int row0  = mtile << 5;

    // cubic through (e, w_edge[e]) for e=0..3 — exact branchless gather
    const float w0 = w_edge[0], w1 = w_edge[1], w2 = w_edge[2], w3 = w_edge[3];
    const float d1 = w1 - w0;
    const float d2 = w2 - 2.f * w1 + w0;
    const float d3 = w3 - 3.f * w2 + 3.f * w1 - w0;
    const float c3 = d3 * (1.f / 6.f);
    const float c2 = 0.5f * d2 - 0.5f * d3;
    const float c1 = d1 - 0.5f * d2 + (1.f / 3.f) * d3;
    const float c0 = w0;

    const size_t bbase = ((size_t)b << 20);          // b * N * N
    const unsigned short* xwb = xw_sw + ((size_t)b << 16);

    f32x4 acc0 = {0.f, 0.f, 0.f, 0.f};
    f32x4 acc1 = acc0, acc2 = acc0, acc3 = acc0;

    for (int c = 0; c < 4; ++c) {
        const int kc = (kh << 9) + (c << 7);         // chunk k base (128 wide)
        if (c) __syncthreads();                      // prior chunk's reads done

        // ---- stage adj & ea in A-frag lane order: frag (mh,kb) 2KB, halves h ----
        #pragma unroll
        for (int f = w; f < 16; f += 4) {
            int mh = f >> 3;
            int kb = (f >> 1) & 3;
            int h  = f & 1;
            int row = row0 + (mh << 4) + m;
            int k   = kc + (kb << 5) + (q << 3) + (h << 2);
            size_t goff = bbase + ((size_t)row << 10) + k;
            int doff = ((mh * 4 + kb) << 11) + (h << 10);
            load_lds16(adj + goff, lds + ADJ_OFF + doff);
            load_lds16(ea  + goff, lds + EA_OFF  + doff);
        }
        // ---- stage xw tiles (already B-frag order, contiguous 1KB each) ----
        #pragma unroll
        for (int f = w; f < 16; f += 4) {
            int kb = f >> 2, n0 = f & 3;
            int kbg = (kh << 4) + (c << 2) + kb;
            load_lds16(xwb + (((kbg << 2) + n0) << 9) + (lane << 3),
                       lds + XW_OFF + (f << 10));
        }
        __syncthreads();                             // drain DMA (vmcnt) + barrier

        // ---- compute: 2 k-steps per wave (kb = wk*2, wk*2+1) ----
        #pragma unroll
        for (int s = 0; s < 2; ++s) {
            int kb = (wk << 1) + s;
            int fbase = ((wm * 4 + kb) << 11) + (lane << 4);
            f32x4 alo = *(const f32x4*)(lds + ADJ_OFF + fbase);
            f32x4 ahi = *(const f32x4*)(lds + ADJ_OFF + fbase + 1024);
            i32x4 elo = *(const i32x4*)(lds + EA_OFF + fbase);
            i32x4 ehi = *(const i32x4*)(lds + EA_OFF + fbase + 1024);

            #define WSEL(ev) __builtin_fmaf(__builtin_fmaf(__builtin_fmaf(c3, (float)(ev), c2), (float)(ev), c1), (float)(ev), c0)
            float p0 = alo[0] * WSEL(elo[0]);
            float p1 = alo[1] * WSEL(elo[1]);
            float p2 = alo[2] * WSEL(elo[2]);
            float p3 = alo[3] * WSEL(elo[3]);
            float p4 = ahi[0] * WSEL(ehi[0]);
            float p5 = ahi[1] * WSEL(ehi[1]);
            float p6 = ahi[2] * WSEL(ehi[2]);
            float p7 = ahi[3] * WSEL(ehi[3]);
            #undef WSEL

            union { int i[4]; short8 s8; } af;
            af.i[0] = __builtin_amdgcn_perm(__float_as_uint(p1), __float_as_uint(p0), 0x07060302u);
            af.i[1] = __builtin_amdgcn_perm(__float_as_uint(p3), __float_as_uint(p2), 0x07060302u);
            af.i[2] = __builtin_amdgcn_perm(__float_as_uint(p5), __float_as_uint(p4), 0x07060302u);
            af.i[3] = __builtin_amdgcn_perm(__float_as_uint(p7), __float_as_uint(p6), 0x07060302u);

            const char* xbase = lds + XW_OFF + ((kb << 2) << 10) + (lane << 4);
            short8 bf0 = *(const short8*)(xbase);
            short8 bf1 = *(const short8*)(xbase + 1024);
            short8 bf2 = *(const short8*)(xbase + 2048);
            short8 bf3 = *(const short8*)(xbase + 3072);

            acc0 = __builtin_amdgcn_mfma_f32_16x16x32_bf16(af.s8, bf0, acc0, 0, 0, 0);
            acc1 = __builtin_amdgcn_mfma_f32_16x16x32_bf16(af.s8, bf1, acc1, 0, 0, 0);
            acc2 = __builtin_amdgcn_mfma_f32_16x16x32_bf16(af.s8, bf2, acc2, 0, 0, 0);
            acc3 = __builtin_amdgcn_mfma_f32_16x16x32_bf16(af.s8, bf3, acc3, 0, 0, 0);
        }
    }

    // ---- combine wk pairs via LDS (stride-68, conflict-free), atomicAdd out ----
    __syncthreads();
    float* scratch = (float*)lds;                    // reuse staging area
    if (wk == 1) {
        float* buf = scratch + wm * 1088;
        #pragma unroll
        for (int rg = 0; rg < 4; ++rg) {
            int rbase = (q * 4 + rg) * 68 + m;
            buf[rbase]      = acc0[rg];
            buf[rbase + 16] = acc1[rg];
            buf[rbase + 32] = acc2[rg];
            buf[rbase + 48] = acc3[rg];
        }
    }
    __syncthreads();
    if (wk == 0) {
        const float* buf = scratch + wm * 1088;
        float* obase = out + (((size_t)b << 10) + row0 + (wm << 4)) * 64;
        #pragma unroll
        for (int rg = 0; rg < 4; ++rg) {
            int rpad = (q * 4 + rg) * 68 + m;
            int rout = (q * 4 + rg) * 64 + m;
            #pragma unroll
            for (int n0 = 0; n0 < 4; ++n0) {
                float v = (n0 == 0 ? acc0[rg] : n0 == 1 ? acc1[rg] : n0 == 2 ? acc2[rg] : acc3[rg]);
                v += buf[rpad + n0 * 16];
                atomicAdd(obase + rout + n0 * 16, v);
            }
        }
    }
}

extern "C" void kernel_launch(void* const* d_in, const int* in_sizes, int n_in,
                              void* d_out, int out_size, void* d_ws, size_t ws_size,
                              hipStream_t stream) {
    const float* x      = (const float*)d_in[0];
    const float* adj    = (const float*)d_in[1];
    const int*   ea     = (const int*)  d_in[2];
    const float* W_rel  = (const float*)d_in[3];
    const float* b_rel  = (const float*)d_in[4];
    const float* W_root = (const float*)d_in[5];
    const float* w_edge = (const float*)d_in[6];
    float* out = (float*)d_out;

    unsigned short* xw_sw = (unsigned short*)d_ws;   // B*N*C bf16 = 2 MiB

    precompute<<<BB * NN / 16, 256, 0, stream>>>(x, W_rel, W_root, b_rel, xw_sw, out);
    gnn_mfma<<<BB * (NN / 32) * 2, 256, 0, stream>>>(adj, ea, w_edge, xw_sw, out);
}